// Round 10
// baseline (179.702 us; speedup 1.0000x reference)
//
#include <hip/hip_runtime.h>
#include <hip/hip_bf16.h>
#include <cstdint>

#define BATCH 8192
#define IN_F  4096
#define OUT_F 128
#define KSPLIT 8
#define KSLICE (IN_F / KSPLIT)   // 512
#define NKS    (KSLICE / 32)     // 16 k-steps of 32 per wave
// float32-rounded decay constants (tau_fac=100, tau_dep=200)
#define FD 0.99004983374916811f
#define DD 0.99501247919268232f

typedef __attribute__((ext_vector_type(4))) float f32x4;
typedef __attribute__((ext_vector_type(8))) float f32x8;
typedef __attribute__((ext_vector_type(8))) short bf16x8;

__device__ __forceinline__ unsigned short f2bf(float f){
  union { float f; unsigned u; } v; v.f = f;
  unsigned u = v.u;
  return (unsigned short)((u + 0x7FFFu + ((u >> 16) & 1u)) >> 16);  // RNE
}

// Pre-shuffle weight[128][4096] f32 -> fragment-major bf16 (proven R1-R9).
// Frag id f = (ks*8 + ct)*64 + l ; lane l holds weight[ct*16+(l&15)][ks*32+(l>>4)*8 + j]
__global__ __launch_bounds__(256) void prep_weight_kernel(const float* __restrict__ w,
                                                          unsigned short* __restrict__ wf){
  const int f  = blockIdx.x * 256 + threadIdx.x;   // 0..65535
  const int l  = f & 63;
  const int ct = (f >> 6) & 7;
  const int ks = f >> 9;                           // 0..127
  const int row = ct * 16 + (l & 15);
  const int k   = ks * 32 + ((l >> 4) << 3);
  const f32x4* src = reinterpret_cast<const f32x4*>(w + (size_t)row * IN_F + k);
  f32x4 a = src[0], b = src[1];
  union { bf16x8 v; unsigned short s[8]; } o;
  o.s[0]=f2bf(a[0]); o.s[1]=f2bf(a[1]); o.s[2]=f2bf(a[2]); o.s[3]=f2bf(a[3]);
  o.s[4]=f2bf(b[0]); o.s[5]=f2bf(b[1]); o.s[6]=f2bf(b[2]); o.s[7]=f2bf(b[3]);
  *reinterpret_cast<bf16x8*>(wf + (size_t)f * 8) = o.v;
}

// Barrier-free, LDS-free fused kernel with vmcnt-FIFO-disciplined issue order
// and a 2-deep HBM pipeline. Wave = 16 rows x 512-K slice (R4-proven mapping,
// KSPLIT=8 -> 1024 blocks x 4 waves). Per iteration:
//   [8 B-frag loads (L2-hot wf)] -> [elementwise on A(i) (landed 2 iters ago)]
//   -> [un/xn stores] -> [A(i+2) issue] -> [8 MFMA (waits B only, vmcnt~7)]
// No wait in the loop ever drains the in-flight A HBM loads.
__global__ __launch_bounds__(256, 3) void stp_fused7(
    const float* __restrict__ pre, const float* __restrict__ uin,
    const float* __restrict__ xin, const unsigned short* __restrict__ wf,
    float* __restrict__ out, float* __restrict__ un_out, float* __restrict__ xn_out)
{
  const int tid = threadIdx.x;
  const int wv  = tid >> 6;
  const int l   = tid & 63;

  const int kslice  = blockIdx.x & (KSPLIT - 1);
  const int rowBase = (blockIdx.x >> 3) * 64 + wv * 16;   // wave's 16-row group
  const size_t base = (size_t)(rowBase + (l & 15)) * IN_F + kslice * KSLICE + ((l >> 4) << 3);

  const bf16x8* wfp = reinterpret_cast<const bf16x8*>(wf);

  f32x4 acc[8];
  #pragma unroll
  for (int ct = 0; ct < 8; ++ct) acc[ct] = (f32x4){0.f,0.f,0.f,0.f};

  // prologue: 2-deep A pipeline
  f32x8 s0 = *reinterpret_cast<const f32x8*>(pre + base);
  f32x8 u0 = *reinterpret_cast<const f32x8*>(uin + base);
  f32x8 x0 = *reinterpret_cast<const f32x8*>(xin + base);
  f32x8 s1 = *reinterpret_cast<const f32x8*>(pre + base + 32);
  f32x8 u1 = *reinterpret_cast<const f32x8*>(uin + base + 32);
  f32x8 x1 = *reinterpret_cast<const f32x8*>(xin + base + 32);

  #pragma unroll 2
  for (int ks = 0; ks < NKS; ++ks){
    const size_t g   = base + (size_t)(ks << 5);
    const int    gks = kslice * NKS + ks;          // global k-step 0..127

    // ---- [1] all 8 B-fragment loads first (L2-hot; oldest in vmcnt FIFO) ----
    bf16x8 b[8];
    #pragma unroll
    for (int ct = 0; ct < 8; ++ct)
      b[ct] = wfp[(size_t)((gks * 8 + ct) << 6) + l];

    // ---- [2] elementwise on A(i): landed 2 iterations ago ----
    f32x8 un, xn;
    union { bf16x8 v; unsigned short s[8]; } af;
    #pragma unroll
    for (int j = 0; j < 8; ++j){
      const float s = s0[j], u = u0[j], x = x0[j];
      af.s[j] = f2bf(u * x * s);
      const float ufd = u * FD;
      const float unj = ufd + 0.5f * (1.0f - ufd) * s;
      un[j] = unj;
      xn[j] = x * DD + (1.0f - x) * DD * (1.0f - s * unj);
    }

    // ---- [3] state stores ----
    *reinterpret_cast<f32x8*>(un_out + g) = un;
    *reinterpret_cast<f32x8*>(xn_out + g) = xn;

    // ---- [4] A(i+2) issue: rides in flight for 2 full iterations ----
    f32x8 s2, u2, x2;
    if (ks + 2 < NKS){
      const size_t g2 = base + (size_t)((ks + 2) << 5);
      s2 = *reinterpret_cast<const f32x8*>(pre + g2);
      u2 = *reinterpret_cast<const f32x8*>(uin + g2);
      x2 = *reinterpret_cast<const f32x8*>(xin + g2);
    }

    // ---- [5] MFMA: waits only the B-frags (stores/A stay outstanding) ----
    #pragma unroll
    for (int ct = 0; ct < 8; ++ct)
      acc[ct] = __builtin_amdgcn_mfma_f32_16x16x32_bf16(af.v, b[ct], acc[ct], 0, 0, 0);

    // rotate pipeline
    s0 = s1; u0 = u1; x0 = x1;
    s1 = s2; u1 = u2; x1 = x2;
  }

  // ---- epilogue: C/D layout col=lane&15, row=(lane>>4)*4+reg; 8-way K-split
  // partials combined with f32 HW atomics (out pre-zeroed by hipMemsetAsync) ----
  const int col0 = l & 15;
  const int r0   = rowBase + ((l >> 4) << 2);
  #pragma unroll
  for (int ct = 0; ct < 8; ++ct){
    #pragma unroll
    for (int rg = 0; rg < 4; ++rg){
      unsafeAtomicAdd(&out[(size_t)(r0 + rg) * OUT_F + ct * 16 + col0], acc[ct][rg]);
    }
  }
}

extern "C" void kernel_launch(void* const* d_in, const int* in_sizes, int n_in,
                              void* d_out, int out_size, void* d_ws, size_t ws_size,
                              hipStream_t stream){
  const float* pre = (const float*)d_in[0];
  const float* w   = (const float*)d_in[1];
  const float* u   = (const float*)d_in[2];
  const float* x   = (const float*)d_in[3];
  float* out    = (float*)d_out;
  float* un_out = out + (size_t)BATCH * OUT_F;
  float* xn_out = un_out + (size_t)BATCH * IN_F;
  unsigned short* wf = (unsigned short*)d_ws;   // 1 MiB (proven R9 ws usage)

  // zero the GEMM output region (atomic accumulation target)
  hipMemsetAsync(out, 0, (size_t)BATCH * OUT_F * sizeof(float), stream);

  prep_weight_kernel<<<256, 256, 0, stream>>>(w, wf);
  stp_fused7<<<(BATCH / 64) * KSPLIT, 256, 0, stream>>>(pre, u, x, wf, out, un_out, xn_out);
}